// Round 10
// baseline (433.297 us; speedup 1.0000x reference)
//
#include <hip/hip_runtime.h>

#define ND 32
#define ED 8
#define NL 4
#define NG 1000
#define NBC_MAX 512   // max coarse buckets (N/256)
#define CHUNK 8192    // edges per k_binA block
#define CHUNK_H 4096  // edges per k_chist block
#define NBLK 64       // block size for small node-grid kernels
#define SPLIT 16      // blocks per bucket in k_edge_bucket (parallelism)

typedef unsigned short u16;

// XCD-contiguous swizzle: blocks on XCD (b%8) get a contiguous work range.
__device__ __forceinline__ int xcd_swizzle(int b, int nb) {
  int per = nb >> 3;
  return (b < (per << 3)) ? ((b & 7) * per + (b >> 3)) : b;
}

// ---------- bf16 helpers (storage bf16, compute fp32) ----------
// HW pack: v_cvt_pk_bf16_f32 converts 2 f32 -> 2 bf16 (RNE) in 1 inst.

__device__ __forceinline__ unsigned pack2(float a, float b) {
  unsigned r;
  asm("v_cvt_pk_bf16_f32 %0, %1, %2" : "=v"(r) : "v"(a), "v"(b));
  return r;
}
// round f32 to the value it would have after bf16 store+load
__device__ __forceinline__ float bf_round(float f) {
  unsigned r;
  asm("v_cvt_pk_bf16_f32 %0, %1, %2" : "=v"(r) : "v"(f), "v"(f));
  return __uint_as_float(r << 16);
}
__device__ __forceinline__ void cvt8(uint4 p, float* o) {
  o[0] = __uint_as_float(p.x << 16); o[1] = __uint_as_float(p.x & 0xffff0000u);
  o[2] = __uint_as_float(p.y << 16); o[3] = __uint_as_float(p.y & 0xffff0000u);
  o[4] = __uint_as_float(p.z << 16); o[5] = __uint_as_float(p.z & 0xffff0000u);
  o[6] = __uint_as_float(p.w << 16); o[7] = __uint_as_float(p.w & 0xffff0000u);
}
__device__ __forceinline__ uint4 pack8(const float* v) {
  uint4 o;
  o.x = pack2(v[0], v[1]); o.y = pack2(v[2], v[3]);
  o.z = pack2(v[4], v[5]); o.w = pack2(v[6], v[7]);
  return o;
}

// Native LDS float add: workgroup scope + relaxed ordering lowers to
// ds_add_f32 (no CAS retry loop). Plain atomicAdd(float*) without
// -munsafe-fp-atomics compiles to a ds_cmpst CAS LOOP, which under the
// ~8-way same-dst contention of sorted edges saturates the LDS pipe —
// the ~60us/layer wall seen in rounds 1-9.
__device__ __forceinline__ void lds_fadd(float* p, float v) {
  __hip_atomic_fetch_add(p, v, __ATOMIC_RELAXED, __HIP_MEMORY_SCOPE_WORKGROUP);
}

// ---------- init: h = x@Wn+bn; zs/zd projections for layer-0 edge MLP ----------

__global__ void k_init_h(const float* __restrict__ x,
                         const float* __restrict__ W,   // [2][ND]
                         const float* __restrict__ b,   // [ND]
                         const float* __restrict__ We,  // [72][ED] layer 0
                         const float* __restrict__ be,  // [ED] layer 0
                         u16* __restrict__ h,
                         u16* __restrict__ zs, u16* __restrict__ zd,
                         int N) {
  int n = xcd_swizzle(blockIdx.x, gridDim.x) * blockDim.x + threadIdx.x;
  if (n >= N) return;
  float x0 = x[2 * n], x1 = x[2 * n + 1];
  float v[ND];
#pragma unroll
  for (int d = 0; d < ND; ++d) v[d] = fmaf(x0, W[d], fmaf(x1, W[ND + d], b[d]));
#pragma unroll
  for (int d = 0; d < ND; ++d) v[d] = bf_round(v[d]);
  uint4* h4 = reinterpret_cast<uint4*>(h + (size_t)n * ND);
#pragma unroll
  for (int q = 0; q < 4; ++q) h4[q] = pack8(&v[q * 8]);
  float zsv[ED], zdv[ED];
#pragma unroll
  for (int j = 0; j < ED; ++j) { zsv[j] = 0.0f; zdv[j] = be[j]; }
#pragma unroll
  for (int k = 0; k < ND; ++k)
#pragma unroll
    for (int j = 0; j < ED; ++j) {
      zsv[j] = fmaf(v[k], We[k * ED + j], zsv[j]);
      zdv[j] = fmaf(v[k], We[(ND + k) * ED + j], zdv[j]);
    }
  *reinterpret_cast<uint4*>(zs + (size_t)n * ED) = pack8(zsv);
  *reinterpret_cast<uint4*>(zd + (size_t)n * ED) = pack8(zdv);
}

// ---------- CSR-free binned counting sort by dst ----------

__global__ void k_chist(const int* __restrict__ dst, int* __restrict__ bcnt,
                        int E, int nbc) {
  __shared__ int lcnt[NBC_MAX];
  for (int b = threadIdx.x; b < nbc; b += blockDim.x) lcnt[b] = 0;
  __syncthreads();
  int e0 = blockIdx.x * CHUNK_H;
  int e1 = min(e0 + CHUNK_H, E);
  for (int i = e0 + threadIdx.x; i < e1; i += blockDim.x)
    atomicAdd(&lcnt[dst[i] >> 8], 1);
  __syncthreads();
  for (int b = threadIdx.x; b < nbc; b += blockDim.x)
    if (lcnt[b]) atomicAdd(&bcnt[b], lcnt[b]);
}

__global__ void k_cscan(const int* __restrict__ bcnt, int* __restrict__ bbase,
                        int nbc) {
  __shared__ int s[NBC_MAX];
  int tid = threadIdx.x;
  if (nbc <= NBC_MAX) {
    int v = (tid < nbc) ? bcnt[tid] : 0;
    s[tid] = v;
    __syncthreads();
    for (int st = 1; st < NBC_MAX; st <<= 1) {
      int t = (tid >= st) ? s[tid - st] : 0;
      __syncthreads();
      s[tid] += t;
      __syncthreads();
    }
    if (tid < nbc) bbase[tid] = s[tid] - v;
    if (tid == nbc - 1) bbase[nbc] = s[tid];
  } else if (tid == 0) {
    int run = 0;
    for (int i = 0; i < nbc; ++i) { bbase[i] = run; run += bcnt[i]; }
    bbase[nbc] = run;
  }
}

// packed 8-B record: .x = src | (dst_local << 24)
__global__ void k_binA(const int* __restrict__ src, const int* __restrict__ dst,
                       const float* __restrict__ ea,
                       const int* __restrict__ bbase, int* __restrict__ cursor_c,
                       uint2* __restrict__ binned, int E, int nbc) {
  __shared__ int lcnt[NBC_MAX];
  __shared__ int lbase[NBC_MAX];
  for (int b = threadIdx.x; b < nbc; b += blockDim.x) lcnt[b] = 0;
  __syncthreads();
  int e0 = blockIdx.x * CHUNK;
  int e1 = min(e0 + CHUNK, E);
  for (int i = e0 + threadIdx.x; i < e1; i += blockDim.x)
    atomicAdd(&lcnt[dst[i] >> 8], 1);
  __syncthreads();
  for (int b = threadIdx.x; b < nbc; b += blockDim.x) {
    int c = lcnt[b];
    lbase[b] = c ? (bbase[b] + atomicAdd(&cursor_c[b], c)) : 0;
  }
  __syncthreads();
  for (int i = e0 + threadIdx.x; i < e1; i += blockDim.x) {
    int d = dst[i];
    int pos = atomicAdd(&lbase[d >> 8], 1);
    binned[pos] = make_uint2((unsigned)src[i] | ((unsigned)(d & 255) << 24),
                             __float_as_uint(ea[i]));
  }
}

// Phase B: fine sort within 256-node bucket; materialize sedge {src,dst} (8B),
// sorted edge_attr ea_s (4B), and per-node CSR offsets noffs[] (k_cand only).
__global__ void k_binB(const uint2* __restrict__ binned,
                       const int* __restrict__ bbase,
                       uint2* __restrict__ sedge, float* __restrict__ ea_s,
                       int* __restrict__ noffs,
                       int N) {
  __shared__ int hist[256];
  __shared__ int scn[256];
  int b = blockIdx.x;
  int base = bbase[b], end = bbase[b + 1];
  int node0 = b << 8;
  int nn = min(256, N - node0);
  hist[threadIdx.x] = 0;
  __syncthreads();
  for (int p = base + threadIdx.x; p < end; p += blockDim.x)
    atomicAdd(&hist[binned[p].x >> 24], 1);
  __syncthreads();
  int v = hist[threadIdx.x];
  scn[threadIdx.x] = v;
  __syncthreads();
  for (int st = 1; st < 256; st <<= 1) {
    int t = (threadIdx.x >= (unsigned)st) ? scn[threadIdx.x - st] : 0;
    __syncthreads();
    scn[threadIdx.x] += t;
    __syncthreads();
  }
  int excl = base + scn[threadIdx.x] - v;
  if ((int)threadIdx.x < nn) noffs[node0 + threadIdx.x] = excl;  // CSR start
  if (threadIdx.x == 0) noffs[min(node0 + 256, N)] = end;        // terminator
  hist[threadIdx.x] = excl;  // running cursor
  __syncthreads();
  for (int p = base + threadIdx.x; p < end; p += blockDim.x) {
    uint2 rec = binned[p];  // L2-hot re-read
    int dl = (int)(rec.x >> 24);
    int pos = atomicAdd(&hist[dl], 1);
    sedge[pos] = make_uint2(rec.x & 0xffffffu, (unsigned)(node0 + dl));
    ea_s[pos] = __uint_as_float(rec.y);
  }
}

// ---------- edge-parallel layer: bucket-aligned LDS aggregation ----------
// SPLIT=16 blocks per 256-node bucket; one edge/thread/iter; messages
// accumulate in an 8KB LDS table via NATIVE ds_add_f32 (lds_fadd) after a
// pairwise lane merge; partial table flushed as bf16 with plain coalesced
// stores — zero global atomics (round-6 lesson).
template <int L0>
__global__ void k_edge_bucket(const uint2* __restrict__ sedge,
                              const float* __restrict__ ea_s,  // L0 input
                              u16* __restrict__ e,             // [E][ED] in-place
                              const u16* __restrict__ zs,
                              const u16* __restrict__ zd,
                              const int* __restrict__ bbase,
                              const float* __restrict__ Wei,   // [ED] We_in (L0)
                              const float* __restrict__ bei,   // [ED] be_in (L0)
                              const float* __restrict__ W3,    // [ED][ED]
                              u16* __restrict__ aggp,          // [SPLIT][N][ED] bf16
                              int N) {
  __shared__ float lagg[256 * ED];  // 8KB
  int bb = blockIdx.x;
  int b = bb >> 4, s = bb & 15;     // SPLIT == 16
  int base = bbase[b], end = bbase[b + 1];
  int len = end - base;
  int lo = base + ((len * s) >> 4);
  int hi = base + ((len * (s + 1)) >> 4);
  int tid = threadIdx.x;
  int lane = tid & 63;
  // zero the LDS table
  float4* lz = reinterpret_cast<float4*>(lagg);
#pragma unroll
  for (int q = 0; q < 2; ++q) lz[tid * 2 + q] = make_float4(0.f, 0.f, 0.f, 0.f);
  __syncthreads();
  const uint4* zs4 = reinterpret_cast<const uint4*>(zs);
  const uint4* zd4 = reinterpret_cast<const uint4*>(zd);
  const uint4* e4c = reinterpret_cast<const uint4*>(e);
  uint4* e4 = reinterpret_cast<uint4*>(e);
  for (int p0 = lo; p0 < hi; p0 += 256) {
    int p = p0 + tid;             // wave covers contiguous 64 edges
    bool valid = p < hi;
    int pc = valid ? p : (hi - 1);
    uint2 sd = sedge[pc];
    int src = (int)sd.x, dst = (int)sd.y;
    uint4 ez = zs4[src];
    uint4 dz = zd4[dst];
    float a0 = 0.0f;
    uint4 ee = make_uint4(0, 0, 0, 0);
    if (L0) a0 = ea_s[pc];
    else ee = e4c[pc];
    float zsv[ED], zdv[ED], ein[ED];
    cvt8(ez, zsv);
    cvt8(dz, zdv);
    if (L0) {
#pragma unroll
      for (int j = 0; j < ED; ++j) ein[j] = fmaf(a0, Wei[j], bei[j]);
    } else {
      cvt8(ee, ein);
    }
    float acc[ED];
#pragma unroll
    for (int j = 0; j < ED; ++j) acc[j] = zsv[j] + zdv[j];
#pragma unroll
    for (int k = 0; k < ED; ++k)
#pragma unroll
      for (int j = 0; j < ED; ++j)
        acc[j] = fmaf(ein[k], W3[k * ED + j], acc[j]);
    float r[ED];
#pragma unroll
    for (int j = 0; j < ED; ++j) {
      r[j] = fmaxf(acc[j], 0.0f);
      acc[j] = ein[j] + r[j];  // e residual
    }
    if (valid) e4[p] = pack8(acc);
    // pairwise merge across lanes (2k,2k+1): equal dst -> combine, even adds
    int key = valid ? (dst & 255) : -1;
    int okey = __shfl_xor(key, 1);
    bool same = (okey == key);
#pragma unroll
    for (int j = 0; j < ED; ++j) {
      float ov = __shfl_xor(r[j], 1);
      if (same) r[j] += ov;
    }
    bool do_add = valid && (!same || ((lane & 1) == 0));
    if (do_add) {
      float* ap = lagg + key * ED;
#pragma unroll
      for (int j = 0; j < ED; ++j) lds_fadd(&ap[j], r[j]);
    }
  }
  __syncthreads();
  // flush partial table as bf16: one node per thread, plain coalesced store
  int node0 = b << 8;
  int node = node0 + tid;
  if (node < N) {
    uint4* gp = reinterpret_cast<uint4*>(aggp + ((size_t)s * N + node) * ED);
    *gp = pack8(&lagg[tid * ED]);
  }
}

// ---------- node-parallel layer: streaming node MLP ----------
// Sums the SPLIT bf16 agg partials; h += relu([h,agg]@Wn+bn); emits next zs/zd.
__global__ void k_node_flat(u16* __restrict__ h,
                            const u16* __restrict__ aggp,   // [SPLIT][N][ED] bf16
                            const float* __restrict__ Wn,   // [(ND+ED)][ND]
                            const float* __restrict__ bn,   // [ND]
                            const float* __restrict__ Wen,  // [72][ED] next layer
                            const float* __restrict__ ben,  // [ED] next layer
                            u16* __restrict__ zs_n, u16* __restrict__ zd_n,
                            int N) {
  int n = blockIdx.x * blockDim.x + threadIdx.x;
  if (n >= N) return;
  float av[ED];
#pragma unroll
  for (int j = 0; j < ED; ++j) av[j] = 0.0f;
#pragma unroll
  for (int sI = 0; sI < SPLIT; ++sI) {
    uint4 pv = *reinterpret_cast<const uint4*>(aggp + ((size_t)sI * N + n) * ED);
    float t[ED];
    cvt8(pv, t);
#pragma unroll
    for (int j = 0; j < ED; ++j) av[j] += t[j];
  }
  uint4* h4 = reinterpret_cast<uint4*>(h + (size_t)n * ND);
  float hv[ND];
#pragma unroll
  for (int q = 0; q < 4; ++q) cvt8(h4[q], &hv[q * 8]);
  float acc[ND];
#pragma unroll
  for (int j = 0; j < ND; ++j) acc[j] = bn[j];
#pragma unroll
  for (int k = 0; k < ND; ++k)
#pragma unroll
    for (int j = 0; j < ND; ++j) acc[j] = fmaf(hv[k], Wn[k * ND + j], acc[j]);
#pragma unroll
  for (int k = 0; k < ED; ++k)
#pragma unroll
    for (int j = 0; j < ND; ++j) acc[j] = fmaf(av[k], Wn[(ND + k) * ND + j], acc[j]);
  float hn[ND];
#pragma unroll
  for (int k = 0; k < ND; ++k)
    hn[k] = bf_round(hv[k] + fmaxf(acc[k], 0.0f));  // round as stored
#pragma unroll
  for (int q = 0; q < 4; ++q) h4[q] = pack8(&hn[q * 8]);
  float zsv[ED], zdv[ED];
#pragma unroll
  for (int j = 0; j < ED; ++j) { zsv[j] = 0.0f; zdv[j] = ben[j]; }
#pragma unroll
  for (int k = 0; k < ND; ++k)
#pragma unroll
    for (int j = 0; j < ED; ++j) {
      zsv[j] = fmaf(hn[k], Wen[k * ED + j], zsv[j]);
      zdv[j] = fmaf(hn[k], Wen[(ND + k) * ED + j], zdv[j]);
    }
  *reinterpret_cast<uint4*>(zs_n + (size_t)n * ED) = pack8(zsv);
  *reinterpret_cast<uint4*>(zd_n + (size_t)n * ED) = pack8(zdv);
}

// ---------- fused last layer + readout over candidates only ----------

__device__ __forceinline__ unsigned int enc_f32(float f) {
  unsigned int bits = __float_as_uint(f);
  return (bits & 0x80000000u) ? ~bits : (bits | 0x80000000u);
}
__device__ __forceinline__ float dec_f32(unsigned int u) {
  unsigned int bits = (u & 0x80000000u) ? (u ^ 0x80000000u) : ~u;
  return __uint_as_float(bits);
}

// 16 lanes per candidate, batch-2 load blocks on the CSR walk.
__global__ void k_cand(const u16* __restrict__ h,
                       const u16* __restrict__ e,
                       const u16* __restrict__ zs,
                       const u16* __restrict__ zd,
                       const uint2* __restrict__ sedge,
                       const int* __restrict__ noffs,
                       const int* __restrict__ cand,
                       const int* __restrict__ batch,
                       const float* __restrict__ W3,   // [ED][ED] layer 3
                       const float* __restrict__ Wn,   // [(ND+ED)][ND] layer 3
                       const float* __restrict__ bn,   // [ND] layer 3
                       const float* __restrict__ Wout, // [ND]
                       const float* __restrict__ bout, // [1]
                       float* __restrict__ logits,
                       int* __restrict__ seg,
                       unsigned int* __restrict__ mxu,  // pre-zeroed
                       int NC) {
  int t = blockIdx.x * blockDim.x + threadIdx.x;
  int c = t >> 4, g = t & 15;
  if (c >= NC) return;
  int n = cand[c];
  int o0 = noffs[n], o1 = noffs[n + 1];
  const uint4* h4 = reinterpret_cast<const uint4*>(h + (size_t)n * ND);
  uint4 hq0 = h4[0], hq1 = h4[1], hq2 = h4[2], hq3 = h4[3];
  float zdv[ED];
  cvt8(*reinterpret_cast<const uint4*>(zd + (size_t)n * ED), zdv);
  const uint4* zs4 = reinterpret_cast<const uint4*>(zs);
  const uint4* e4c = reinterpret_cast<const uint4*>(e);
  float av[ED];
#pragma unroll
  for (int j = 0; j < ED; ++j) av[j] = 0.0f;

  auto cand_one = [&](uint4 z_, uint4 e_) {
    float zsv[ED], ein[ED], acc[ED];
    cvt8(z_, zsv);
    cvt8(e_, ein);
#pragma unroll
    for (int j = 0; j < ED; ++j) acc[j] = zsv[j] + zdv[j];
#pragma unroll
    for (int k = 0; k < ED; ++k)
#pragma unroll
      for (int j = 0; j < ED; ++j)
        acc[j] = fmaf(ein[k], W3[k * ED + j], acc[j]);
#pragma unroll
    for (int j = 0; j < ED; ++j) av[j] += fmaxf(acc[j], 0.0f);
  };

  for (int base = o0 + g; base < o1; base += 32) {
    bool v1 = base + 16 < o1;
    int pa = base;
    int pb = v1 ? base + 16 : base;
    int sa = (int)sedge[pa].x, sb = (int)sedge[pb].x;
    uint4 Ea = e4c[pa], Eb = e4c[pb];
    uint4 Za = zs4[sa], Zb = zs4[sb];
    cand_one(Za, Ea);
    if (v1) cand_one(Zb, Eb);
  }
#pragma unroll
  for (int j = 0; j < ED; ++j) {
    av[j] += __shfl_xor(av[j], 1);
    av[j] += __shfl_xor(av[j], 2);
    av[j] += __shfl_xor(av[j], 4);
    av[j] += __shfl_xor(av[j], 8);
  }
  float hv[ND];
  cvt8(hq0, &hv[0]); cvt8(hq1, &hv[8]); cvt8(hq2, &hv[16]); cvt8(hq3, &hv[24]);
  const int j0 = g * 2;  // 2 outputs per lane
  float acc2[2];
#pragma unroll
  for (int jj = 0; jj < 2; ++jj) acc2[jj] = bn[j0 + jj];
#pragma unroll
  for (int k = 0; k < ND; ++k)
#pragma unroll
    for (int jj = 0; jj < 2; ++jj)
      acc2[jj] = fmaf(hv[k], Wn[k * ND + j0 + jj], acc2[jj]);
#pragma unroll
  for (int k = 0; k < ED; ++k)
#pragma unroll
    for (int jj = 0; jj < 2; ++jj)
      acc2[jj] = fmaf(av[k], Wn[(ND + k) * ND + j0 + jj], acc2[jj]);
  float lg = 0.0f;
#pragma unroll
  for (int jj = 0; jj < 2; ++jj)
    lg = fmaf(hv[j0 + jj] + fmaxf(acc2[jj], 0.0f), Wout[j0 + jj], lg);
  lg += __shfl_xor(lg, 1);
  lg += __shfl_xor(lg, 2);
  lg += __shfl_xor(lg, 4);
  lg += __shfl_xor(lg, 8);
  if (g == 0) {
    lg += bout[0];
    logits[c] = lg;
    int gr = batch[n];
    seg[c] = gr;
    atomicMax(&mxu[gr], enc_f32(lg));
  }
}

__global__ void k_expsum(float* __restrict__ logits,
                         const int* __restrict__ seg,
                         const unsigned int* __restrict__ mxu,
                         float* __restrict__ sum,  // pre-zeroed
                         int NC) {
  int c = blockIdx.x * blockDim.x + threadIdx.x;
  if (c >= NC) return;
  int g = seg[c];
  float sh = logits[c] - dec_f32(mxu[g]);
  logits[c] = sh;
  atomicAdd(&sum[g], expf(sh));
}

__global__ void k_final(const float* __restrict__ shifted,
                        const int* __restrict__ seg,
                        const float* __restrict__ sum,
                        float* __restrict__ out, int NC) {
  int c = blockIdx.x * blockDim.x + threadIdx.x;
  if (c >= NC) return;
  out[c] = shifted[c] - logf(sum[seg[c]]);
}

// ---------- launch ----------

extern "C" void kernel_launch(void* const* d_in, const int* in_sizes, int n_in,
                              void* d_out, int out_size, void* d_ws, size_t ws_size,
                              hipStream_t stream) {
  const float* x       = (const float*)d_in[0];
  const float* ea      = (const float*)d_in[1];
  const float* Wn_in   = (const float*)d_in[2];
  const float* bn_in   = (const float*)d_in[3];
  const float* We_in   = (const float*)d_in[4];
  const float* be_in   = (const float*)d_in[5];
  const float* We_l    = (const float*)d_in[6];
  const float* be_l    = (const float*)d_in[7];
  const float* Wn_l    = (const float*)d_in[8];
  const float* bn_l    = (const float*)d_in[9];
  const float* Wout    = (const float*)d_in[10];
  const float* bout    = (const float*)d_in[11];
  const int* edge_index= (const int*)d_in[12];
  const int* batch     = (const int*)d_in[13];
  const int* cand      = (const int*)d_in[14];

  const int N  = in_sizes[13];
  const int E  = in_sizes[1];
  const int NC = in_sizes[14];
  const int nbc = (N + 255) >> 8;

  char* ws = (char*)d_ws;
  uint2* binned = (uint2*)ws; ws += (size_t)E * sizeof(uint2);
  uint2* sedge  = (uint2*)ws; ws += (size_t)E * sizeof(uint2);
  float* ea_s   = (float*)ws; ws += (size_t)E * sizeof(float);
  u16*   h      = (u16*)ws;   ws += (size_t)N * ND * sizeof(u16);
  u16*   e      = (u16*)ws;   ws += (size_t)E * ED * sizeof(u16);
  u16*   zs0    = (u16*)ws;   ws += (size_t)N * ED * sizeof(u16);
  u16*   zd0    = (u16*)ws;   ws += (size_t)N * ED * sizeof(u16);
  u16*   zs1    = (u16*)ws;   ws += (size_t)N * ED * sizeof(u16);
  u16*   zd1    = (u16*)ws;   ws += (size_t)N * ED * sizeof(u16);
  u16*   aggp   = (u16*)ws;   ws += (size_t)SPLIT * N * ED * sizeof(u16);
  int*   noffs  = (int*)ws;   ws += ((size_t)N + 4) * sizeof(int);
  int*   bcnt   = (int*)ws;   ws += (size_t)NBC_MAX * sizeof(int);   // contiguous
  int*   cursor = (int*)ws;   ws += (size_t)NBC_MAX * sizeof(int);   // with bcnt
  int*   bbase  = (int*)ws;   ws += ((size_t)NBC_MAX + 4) * sizeof(int);
  float* logits = (float*)ws; ws += (size_t)NC * sizeof(float);
  int*   seg    = (int*)ws;   ws += (size_t)NC * sizeof(int);
  unsigned int* mxu = (unsigned int*)ws; ws += (size_t)NG * sizeof(unsigned int);
  float* sum    = (float*)ws; ws += (size_t)NG * sizeof(float);  // contiguous w/ mxu

  const int* srcp = edge_index;
  const int* dstp = edge_index + E;
  const int blk = 256;
  const size_t WE_STRIDE = (size_t)(2 * ND + ED) * ED;  // 72*8

  hipMemsetAsync(bcnt, 0, 2 * (size_t)NBC_MAX * sizeof(int), stream);  // bcnt+cursor

  // binned two-phase counting sort (8-B packed records) + CSR offsets
  k_chist<<<(E + CHUNK_H - 1) / CHUNK_H, 1024, 0, stream>>>(dstp, bcnt, E, nbc);
  k_cscan<<<1, NBC_MAX, 0, stream>>>(bcnt, bbase, nbc);
  k_binA<<<(E + CHUNK - 1) / CHUNK, 1024, 0, stream>>>(srcp, dstp, ea, bbase,
                                                       cursor, binned, E, nbc);
  k_binB<<<nbc, 256, 0, stream>>>(binned, bbase, sedge, ea_s, noffs, N);

  k_init_h<<<(N + NBLK - 1) / NBLK, NBLK, 0, stream>>>(x, Wn_in, bn_in, We_l,
                                                       be_l, h, zs0, zd0, N);

  const int ngrid = (N + blk - 1) / blk;
  u16* zsc = zs0; u16* zdc = zd0;
  u16* zsn = zs1; u16* zdn = zd1;
  for (int l = 0; l < NL - 1; ++l) {
    const float* W3 = We_l + l * WE_STRIDE + (size_t)2 * ND * ED;
    const float* Wn = Wn_l + (size_t)l * (ND + ED) * ND;
    const float* bn = bn_l + (size_t)l * ND;
    const float* Wen = We_l + (l + 1) * WE_STRIDE;
    const float* ben = be_l + (size_t)(l + 1) * ED;
    if (l == 0) {
      k_edge_bucket<1><<<nbc * SPLIT, 256, 0, stream>>>(
          sedge, ea_s, e, zsc, zdc, bbase, We_in, be_in, W3, aggp, N);
    } else {
      k_edge_bucket<0><<<nbc * SPLIT, 256, 0, stream>>>(
          sedge, ea_s, e, zsc, zdc, bbase, We_in, be_in, W3, aggp, N);
    }
    k_node_flat<<<ngrid, blk, 0, stream>>>(h, aggp, Wn, bn, Wen, ben,
                                           zsn, zdn, N);
    u16* t;
    t = zsc; zsc = zsn; zsn = t;
    t = zdc; zdc = zdn; zdn = t;
  }

  hipMemsetAsync(mxu, 0, NG * (sizeof(unsigned int) + sizeof(float)), stream);
  {
    const int l = NL - 1;
    const float* W3 = We_l + l * WE_STRIDE + (size_t)2 * ND * ED;
    const float* Wn = Wn_l + (size_t)l * (ND + ED) * ND;
    const float* bn = bn_l + (size_t)l * ND;
    // 16 lanes per candidate
    k_cand<<<((size_t)NC * 16 + 255) / 256, 256, 0, stream>>>(
        h, e, zsc, zdc, sedge, noffs, cand, batch, W3, Wn, bn, Wout, bout,
        logits, seg, mxu, NC);
  }
  k_expsum<<<(NC + blk - 1) / blk, blk, 0, stream>>>(logits, seg, mxu, sum, NC);
  k_final<<<(NC + blk - 1) / blk, blk, 0, stream>>>(logits, seg, sum,
                                                    (float*)d_out, NC);
}

// Round 11
// 329.531 us; speedup vs baseline: 1.3149x; 1.3149x over previous
//
#include <hip/hip_runtime.h>

#define ND 32
#define ED 8
#define NL 4
#define NG 1000
#define NBC_MAX 512   // max coarse buckets (N/256)
#define CHUNK 8192    // edges per k_binA block
#define CHUNK_H 4096  // edges per k_chist block

typedef unsigned short u16;

// XCD-contiguous swizzle: blocks on XCD (b%8) get a contiguous work range.
__device__ __forceinline__ int xcd_swizzle(int b, int nb) {
  int per = nb >> 3;
  return (b < (per << 3)) ? ((b & 7) * per + (b >> 3)) : b;
}

// ---------- bf16 helpers (storage bf16, compute fp32) ----------
// HW pack: v_cvt_pk_bf16_f32 (RNE) — bit-identical to the old software f2bf
// on normal values, 1 inst per 2 floats instead of ~14 ops (verified r4-r10).

__device__ __forceinline__ unsigned pack2(float a, float b) {
  unsigned r;
  asm("v_cvt_pk_bf16_f32 %0, %1, %2" : "=v"(r) : "v"(a), "v"(b));
  return r;
}
// round f32 to the value it would have after bf16 store+load
__device__ __forceinline__ float bf_round(float f) {
  unsigned r;
  asm("v_cvt_pk_bf16_f32 %0, %1, %2" : "=v"(r) : "v"(f), "v"(f));
  return __uint_as_float(r << 16);
}
__device__ __forceinline__ void cvt8(uint4 p, float* o) {
  o[0] = __uint_as_float(p.x << 16); o[1] = __uint_as_float(p.x & 0xffff0000u);
  o[2] = __uint_as_float(p.y << 16); o[3] = __uint_as_float(p.y & 0xffff0000u);
  o[4] = __uint_as_float(p.z << 16); o[5] = __uint_as_float(p.z & 0xffff0000u);
  o[6] = __uint_as_float(p.w << 16); o[7] = __uint_as_float(p.w & 0xffff0000u);
}
__device__ __forceinline__ uint4 pack8(const float* v) {
  uint4 o;
  o.x = pack2(v[0], v[1]); o.y = pack2(v[2], v[3]);
  o.z = pack2(v[4], v[5]); o.w = pack2(v[6], v[7]);
  return o;
}

// ---------- CSR-free binned counting sort by dst ----------

__global__ void k_chist(const int* __restrict__ dst, int* __restrict__ bcnt,
                        int E, int nbc) {
  __shared__ int lcnt[NBC_MAX];
  for (int b = threadIdx.x; b < nbc; b += blockDim.x) lcnt[b] = 0;
  __syncthreads();
  int e0 = blockIdx.x * CHUNK_H;
  int e1 = min(e0 + CHUNK_H, E);
  for (int i = e0 + threadIdx.x; i < e1; i += blockDim.x)
    atomicAdd(&lcnt[dst[i] >> 8], 1);
  __syncthreads();
  for (int b = threadIdx.x; b < nbc; b += blockDim.x)
    if (lcnt[b]) atomicAdd(&bcnt[b], lcnt[b]);
}

__global__ void k_cscan(const int* __restrict__ bcnt, int* __restrict__ bbase,
                        int nbc) {
  __shared__ int s[NBC_MAX];
  int tid = threadIdx.x;
  if (nbc <= NBC_MAX) {
    int v = (tid < nbc) ? bcnt[tid] : 0;
    s[tid] = v;
    __syncthreads();
    for (int st = 1; st < NBC_MAX; st <<= 1) {
      int t = (tid >= st) ? s[tid - st] : 0;
      __syncthreads();
      s[tid] += t;
      __syncthreads();
    }
    if (tid < nbc) bbase[tid] = s[tid] - v;
    if (tid == nbc - 1) bbase[nbc] = s[tid];
  } else if (tid == 0) {
    int run = 0;
    for (int i = 0; i < nbc; ++i) { bbase[i] = run; run += bcnt[i]; }
    bbase[nbc] = run;
  }
}

// packed 8-B record: .x = src | (dst_local << 24)
__global__ void k_binA(const int* __restrict__ src, const int* __restrict__ dst,
                       const float* __restrict__ ea,
                       const int* __restrict__ bbase, int* __restrict__ cursor_c,
                       uint2* __restrict__ binned, int E, int nbc) {
  __shared__ int lcnt[NBC_MAX];
  __shared__ int lbase[NBC_MAX];
  for (int b = threadIdx.x; b < nbc; b += blockDim.x) lcnt[b] = 0;
  __syncthreads();
  int e0 = blockIdx.x * CHUNK;
  int e1 = min(e0 + CHUNK, E);
  for (int i = e0 + threadIdx.x; i < e1; i += blockDim.x)
    atomicAdd(&lcnt[dst[i] >> 8], 1);
  __syncthreads();
  for (int b = threadIdx.x; b < nbc; b += blockDim.x) {
    int c = lcnt[b];
    lbase[b] = c ? (bbase[b] + atomicAdd(&cursor_c[b], c)) : 0;
  }
  __syncthreads();
  for (int i = e0 + threadIdx.x; i < e1; i += blockDim.x) {
    int d = dst[i];
    int pos = atomicAdd(&lbase[d >> 8], 1);
    binned[pos] = make_uint2((unsigned)src[i] | ((unsigned)(d & 255) << 24),
                             __float_as_uint(ea[i]));
  }
}

// Phase B: fine sort within 256-node bucket; materialize ssrc (4B), sorted
// edge_attr ea_s (4B), per-node CSR offsets noffs[]; FUSED with k_init_h
// (same 256-nodes-per-block shape): h = x@Wn+bn and layer-0 zs/zd
// projections — saves one dispatch boundary.
__global__ void k_binB_init(const uint2* __restrict__ binned,
                            const int* __restrict__ bbase,
                            int* __restrict__ ssrc, float* __restrict__ ea_s,
                            int* __restrict__ noffs,
                            const float* __restrict__ x,
                            const float* __restrict__ Wni,  // [2][ND]
                            const float* __restrict__ bni,  // [ND]
                            const float* __restrict__ We0,  // [72][ED] layer 0
                            const float* __restrict__ be0,  // [ED] layer 0
                            u16* __restrict__ h,
                            u16* __restrict__ zs, u16* __restrict__ zd,
                            int N) {
  __shared__ int hist[256];
  __shared__ int scn[256];
  int b = blockIdx.x;
  int base = bbase[b], end = bbase[b + 1];
  int node0 = b << 8;
  int nn = min(256, N - node0);
  hist[threadIdx.x] = 0;
  __syncthreads();
  for (int p = base + threadIdx.x; p < end; p += blockDim.x)
    atomicAdd(&hist[binned[p].x >> 24], 1);
  __syncthreads();
  int v = hist[threadIdx.x];
  scn[threadIdx.x] = v;
  __syncthreads();
  for (int st = 1; st < 256; st <<= 1) {
    int t = (threadIdx.x >= (unsigned)st) ? scn[threadIdx.x - st] : 0;
    __syncthreads();
    scn[threadIdx.x] += t;
    __syncthreads();
  }
  int excl = base + scn[threadIdx.x] - v;
  if ((int)threadIdx.x < nn) noffs[node0 + threadIdx.x] = excl;  // CSR start
  if (threadIdx.x == 0) noffs[min(node0 + 256, N)] = end;        // terminator
  hist[threadIdx.x] = excl;  // running cursor
  __syncthreads();
  for (int p = base + threadIdx.x; p < end; p += blockDim.x) {
    uint2 rec = binned[p];  // L2-hot re-read
    int dl = (int)(rec.x >> 24);
    int pos = atomicAdd(&hist[dl], 1);
    ssrc[pos] = (int)(rec.x & 0xffffffu);
    ea_s[pos] = __uint_as_float(rec.y);
  }
  // ---- fused init for this block's 256 nodes (independent of sort) ----
  int n = node0 + threadIdx.x;
  if (n < N) {
    float x0 = x[2 * n], x1 = x[2 * n + 1];
    float vv[ND];
#pragma unroll
    for (int d = 0; d < ND; ++d)
      vv[d] = bf_round(fmaf(x0, Wni[d], fmaf(x1, Wni[ND + d], bni[d])));
    uint4* h4 = reinterpret_cast<uint4*>(h + (size_t)n * ND);
#pragma unroll
    for (int q = 0; q < 4; ++q) h4[q] = pack8(&vv[q * 8]);
    float zsv[ED], zdv[ED];
#pragma unroll
    for (int j = 0; j < ED; ++j) { zsv[j] = 0.0f; zdv[j] = be0[j]; }
#pragma unroll
    for (int k = 0; k < ND; ++k)
#pragma unroll
      for (int j = 0; j < ED; ++j) {
        zsv[j] = fmaf(vv[k], We0[k * ED + j], zsv[j]);
        zdv[j] = fmaf(vv[k], We0[(ND + k) * ED + j], zdv[j]);
      }
    *reinterpret_cast<uint4*>(zs + (size_t)n * ED) = pack8(zsv);
    *reinterpret_cast<uint4*>(zd + (size_t)n * ED) = pack8(zdv);
  }
}

// ---------- fused layer kernel: 8 lanes per node, depth-2 pipelined ----------
// (Round-3 structure — best measured: 58us/layer, total 339.7us.) Lanes
// g=0..7 stride the node's CSR segment; two (ssrc,e/ea) slots and one
// zs-gather slot stay in flight. Edge MLP on the fly, e updated in place,
// agg reduced via shfl_xor, node MLP and next-layer zs/zd projections
// sliced 4 outputs/lane. zs/zd ping-pong removes the cross-node race.
template <int L0>
__global__ void k_layer(u16* __restrict__ h,
                        u16* __restrict__ e,            // [E][ED] bf16, in-place
                        const float* __restrict__ ea_s, // sorted edge_attr (L0)
                        const int* __restrict__ ssrc,
                        const int* __restrict__ noffs,
                        const u16* __restrict__ zs,
                        const u16* __restrict__ zd,
                        const float* __restrict__ Wei,  // [ED] We_in (L0 only)
                        const float* __restrict__ bei,  // [ED] be_in (L0 only)
                        const float* __restrict__ W3,   // [ED][ED] this layer
                        const float* __restrict__ Wn,   // [(ND+ED)][ND]
                        const float* __restrict__ bn,   // [ND]
                        const float* __restrict__ Wen,  // [72][ED] next layer
                        const float* __restrict__ ben,  // [ED] next layer
                        u16* __restrict__ zs_n, u16* __restrict__ zd_n,
                        int N) {
  int t = xcd_swizzle(blockIdx.x, gridDim.x) * blockDim.x + threadIdx.x;
  int n = t >> 3;   // node index (32 nodes per 256-thread block)
  int g = t & 7;    // lane within 8-lane group
  if (n >= N) return;
  int o0 = noffs[n], o1 = noffs[n + 1];
  float zdv[ED];
  cvt8(*reinterpret_cast<const uint4*>(zd + (size_t)n * ED), zdv);
  const uint4* zs4 = reinterpret_cast<const uint4*>(zs);
  const uint4* e4c = reinterpret_cast<const uint4*>(e);
  uint4* e4 = reinterpret_cast<uint4*>(e);
  float av[ED];
#pragma unroll
  for (int j = 0; j < ED; ++j) av[j] = 0.0f;

  // software pipeline: slot A = current (zs resolved), slot B = next (s,e
  // loaded), slot C loaded in-loop.
  int p = o0 + g;
  int sA = 0, sB = 0;
  uint4 eA = make_uint4(0, 0, 0, 0), eB = make_uint4(0, 0, 0, 0);
  float aA = 0.0f, aB = 0.0f;
  uint4 zA = make_uint4(0, 0, 0, 0);
  if (p < o1) {
    sA = ssrc[p];
    if (L0) aA = ea_s[p]; else eA = e4c[p];
    zA = zs4[sA];
  }
  if (p + 8 < o1) {
    sB = ssrc[p + 8];
    if (L0) aB = ea_s[p + 8]; else eB = e4c[p + 8];
  }
  for (; p < o1; ) {
    int pn = p + 8, pc = p + 16;
    // issue next-iteration zs gather and iteration-after-next stream loads
    uint4 zB = make_uint4(0, 0, 0, 0);
    if (pn < o1) zB = zs4[sB];
    int sC = 0; uint4 eC = make_uint4(0, 0, 0, 0); float aC = 0.0f;
    if (pc < o1) {
      sC = ssrc[pc];
      if (L0) aC = ea_s[pc]; else eC = e4c[pc];
    }
    // compute current edge
    float zsv[ED], ein[ED], acc[ED];
    cvt8(zA, zsv);
    if (L0) {
#pragma unroll
      for (int j = 0; j < ED; ++j) ein[j] = fmaf(aA, Wei[j], bei[j]);
    } else {
      cvt8(eA, ein);
    }
#pragma unroll
    for (int j = 0; j < ED; ++j) acc[j] = zsv[j] + zdv[j];
#pragma unroll
    for (int k = 0; k < ED; ++k)
#pragma unroll
      for (int j = 0; j < ED; ++j)
        acc[j] = fmaf(ein[k], W3[k * ED + j], acc[j]);
    float eo[ED];
#pragma unroll
    for (int j = 0; j < ED; ++j) {
      float r = fmaxf(acc[j], 0.0f);
      av[j] += r;
      eo[j] = ein[j] + r;
    }
    e4[p] = pack8(eo);
    // rotate pipeline
    p = pn;
    sA = sB; eA = eB; aA = aB; zA = zB;
    sB = sC; eB = eC; aB = aC;
  }
  // reduce aggregate across the 8-lane group
#pragma unroll
  for (int j = 0; j < ED; ++j) {
    av[j] += __shfl_xor(av[j], 1);
    av[j] += __shfl_xor(av[j], 2);
    av[j] += __shfl_xor(av[j], 4);
  }
  // node MLP, sliced: lane g computes outputs [4g, 4g+4)
  uint4* h4 = reinterpret_cast<uint4*>(h + (size_t)n * ND);
  float hv[ND];
#pragma unroll
  for (int q = 0; q < 4; ++q) cvt8(h4[q], &hv[q * 8]);
  const int j0 = g * 4;
  float acc4[4];
#pragma unroll
  for (int jj = 0; jj < 4; ++jj) acc4[jj] = bn[j0 + jj];
#pragma unroll
  for (int k = 0; k < ND; ++k)
#pragma unroll
    for (int jj = 0; jj < 4; ++jj)
      acc4[jj] = fmaf(hv[k], Wn[k * ND + j0 + jj], acc4[jj]);
#pragma unroll
  for (int k = 0; k < ED; ++k)
#pragma unroll
    for (int jj = 0; jj < 4; ++jj)
      acc4[jj] = fmaf(av[k], Wn[(ND + k) * ND + j0 + jj], acc4[jj]);
  float hn4[4];
#pragma unroll
  for (int jj = 0; jj < 4; ++jj)
    hn4[jj] = bf_round(hv[j0 + jj] + fmaxf(acc4[jj], 0.0f));  // round as stored
  reinterpret_cast<uint2*>(h + (size_t)n * ND)[g] =
      make_uint2(pack2(hn4[0], hn4[1]), pack2(hn4[2], hn4[3]));
  // next-layer zs/zd projections: partial over this lane's 4 hn rows,
  // group-reduce; lanes 0/1 write the 16B results.
  float pz[2 * ED];
#pragma unroll
  for (int j = 0; j < 2 * ED; ++j) pz[j] = 0.0f;
#pragma unroll
  for (int kk = 0; kk < 4; ++kk) {
    float hk = hn4[kk];
    int krow = j0 + kk;
#pragma unroll
    for (int j = 0; j < ED; ++j) {
      pz[j] = fmaf(hk, Wen[krow * ED + j], pz[j]);
      pz[ED + j] = fmaf(hk, Wen[(ND + krow) * ED + j], pz[ED + j]);
    }
  }
#pragma unroll
  for (int j = 0; j < 2 * ED; ++j) {
    pz[j] += __shfl_xor(pz[j], 1);
    pz[j] += __shfl_xor(pz[j], 2);
    pz[j] += __shfl_xor(pz[j], 4);
  }
  if (g == 0) {
    *reinterpret_cast<uint4*>(zs_n + (size_t)n * ED) = pack8(pz);
  } else if (g == 1) {
    float zdo[ED];
#pragma unroll
    for (int j = 0; j < ED; ++j) zdo[j] = pz[ED + j] + ben[j];
    *reinterpret_cast<uint4*>(zd_n + (size_t)n * ED) = pack8(zdo);
  }
}

// ---------- fused last layer + readout over candidates only ----------

__device__ __forceinline__ unsigned int enc_f32(float f) {
  unsigned int bits = __float_as_uint(f);
  return (bits & 0x80000000u) ? ~bits : (bits | 0x80000000u);
}
__device__ __forceinline__ float dec_f32(unsigned int u) {
  unsigned int bits = (u & 0x80000000u) ? (u ^ 0x80000000u) : ~u;
  return __uint_as_float(bits);
}

// 16 lanes per candidate, batch-2 load blocks on the CSR walk.
__global__ void k_cand(const u16* __restrict__ h,
                       const u16* __restrict__ e,
                       const u16* __restrict__ zs,
                       const u16* __restrict__ zd,
                       const int* __restrict__ ssrc,
                       const int* __restrict__ noffs,
                       const int* __restrict__ cand,
                       const int* __restrict__ batch,
                       const float* __restrict__ W3,   // [ED][ED] layer 3
                       const float* __restrict__ Wn,   // [(ND+ED)][ND] layer 3
                       const float* __restrict__ bn,   // [ND] layer 3
                       const float* __restrict__ Wout, // [ND]
                       const float* __restrict__ bout, // [1]
                       float* __restrict__ logits,
                       int* __restrict__ seg,
                       unsigned int* __restrict__ mxu,  // pre-zeroed
                       int NC) {
  int t = blockIdx.x * blockDim.x + threadIdx.x;
  int c = t >> 4, g = t & 15;
  if (c >= NC) return;
  int n = cand[c];
  int o0 = noffs[n], o1 = noffs[n + 1];
  const uint4* h4 = reinterpret_cast<const uint4*>(h + (size_t)n * ND);
  uint4 hq0 = h4[0], hq1 = h4[1], hq2 = h4[2], hq3 = h4[3];
  float zdv[ED];
  cvt8(*reinterpret_cast<const uint4*>(zd + (size_t)n * ED), zdv);
  const uint4* zs4 = reinterpret_cast<const uint4*>(zs);
  const uint4* e4c = reinterpret_cast<const uint4*>(e);
  float av[ED];
#pragma unroll
  for (int j = 0; j < ED; ++j) av[j] = 0.0f;

  auto cand_one = [&](uint4 z_, uint4 e_) {
    float zsv[ED], ein[ED], acc[ED];
    cvt8(z_, zsv);
    cvt8(e_, ein);
#pragma unroll
    for (int j = 0; j < ED; ++j) acc[j] = zsv[j] + zdv[j];
#pragma unroll
    for (int k = 0; k < ED; ++k)
#pragma unroll
      for (int j = 0; j < ED; ++j)
        acc[j] = fmaf(ein[k], W3[k * ED + j], acc[j]);
#pragma unroll
    for (int j = 0; j < ED; ++j) av[j] += fmaxf(acc[j], 0.0f);
  };

  for (int base = o0 + g; base < o1; base += 32) {
    bool v1 = base + 16 < o1;
    int pa = base;
    int pb = v1 ? base + 16 : base;
    int sa = ssrc[pa], sb = ssrc[pb];
    uint4 Ea = e4c[pa], Eb = e4c[pb];
    uint4 Za = zs4[sa], Zb = zs4[sb];
    cand_one(Za, Ea);
    if (v1) cand_one(Zb, Eb);
  }
#pragma unroll
  for (int j = 0; j < ED; ++j) {
    av[j] += __shfl_xor(av[j], 1);
    av[j] += __shfl_xor(av[j], 2);
    av[j] += __shfl_xor(av[j], 4);
    av[j] += __shfl_xor(av[j], 8);
  }
  float hv[ND];
  cvt8(hq0, &hv[0]); cvt8(hq1, &hv[8]); cvt8(hq2, &hv[16]); cvt8(hq3, &hv[24]);
  const int j0 = g * 2;  // 2 outputs per lane
  float acc2[2];
#pragma unroll
  for (int jj = 0; jj < 2; ++jj) acc2[jj] = bn[j0 + jj];
#pragma unroll
  for (int k = 0; k < ND; ++k)
#pragma unroll
    for (int jj = 0; jj < 2; ++jj)
      acc2[jj] = fmaf(hv[k], Wn[k * ND + j0 + jj], acc2[jj]);
#pragma unroll
  for (int k = 0; k < ED; ++k)
#pragma unroll
    for (int jj = 0; jj < 2; ++jj)
      acc2[jj] = fmaf(av[k], Wn[(ND + k) * ND + j0 + jj], acc2[jj]);
  float lg = 0.0f;
#pragma unroll
  for (int jj = 0; jj < 2; ++jj)
    lg = fmaf(hv[j0 + jj] + fmaxf(acc2[jj], 0.0f), Wout[j0 + jj], lg);
  lg += __shfl_xor(lg, 1);
  lg += __shfl_xor(lg, 2);
  lg += __shfl_xor(lg, 4);
  lg += __shfl_xor(lg, 8);
  if (g == 0) {
    lg += bout[0];
    logits[c] = lg;
    int gr = batch[n];
    seg[c] = gr;
    atomicMax(&mxu[gr], enc_f32(lg));
  }
}

__global__ void k_expsum(float* __restrict__ logits,
                         const int* __restrict__ seg,
                         const unsigned int* __restrict__ mxu,
                         float* __restrict__ sum,  // pre-zeroed
                         int NC) {
  int c = blockIdx.x * blockDim.x + threadIdx.x;
  if (c >= NC) return;
  int g = seg[c];
  float sh = logits[c] - dec_f32(mxu[g]);
  logits[c] = sh;
  atomicAdd(&sum[g], expf(sh));
}

__global__ void k_final(const float* __restrict__ shifted,
                        const int* __restrict__ seg,
                        const float* __restrict__ sum,
                        float* __restrict__ out, int NC) {
  int c = blockIdx.x * blockDim.x + threadIdx.x;
  if (c >= NC) return;
  out[c] = shifted[c] - logf(sum[seg[c]]);
}

// ---------- launch ----------

extern "C" void kernel_launch(void* const* d_in, const int* in_sizes, int n_in,
                              void* d_out, int out_size, void* d_ws, size_t ws_size,
                              hipStream_t stream) {
  const float* x       = (const float*)d_in[0];
  const float* ea      = (const float*)d_in[1];
  const float* Wn_in   = (const float*)d_in[2];
  const float* bn_in   = (const float*)d_in[3];
  const float* We_in   = (const float*)d_in[4];
  const float* be_in   = (const float*)d_in[5];
  const float* We_l    = (const float*)d_in[6];
  const float* be_l    = (const float*)d_in[7];
  const float* Wn_l    = (const float*)d_in[8];
  const float* bn_l    = (const float*)d_in[9];
  const float* Wout    = (const float*)d_in[10];
  const float* bout    = (const float*)d_in[11];
  const int* edge_index= (const int*)d_in[12];
  const int* batch     = (const int*)d_in[13];
  const int* cand      = (const int*)d_in[14];

  const int N  = in_sizes[13];
  const int E  = in_sizes[1];
  const int NC = in_sizes[14];
  const int nbc = (N + 255) >> 8;

  char* ws = (char*)d_ws;
  uint2* binned = (uint2*)ws; ws += (size_t)E * sizeof(uint2);
  int*   ssrc   = (int*)ws;   ws += (size_t)E * sizeof(int);
  float* ea_s   = (float*)ws; ws += (size_t)E * sizeof(float);
  u16*   h      = (u16*)ws;   ws += (size_t)N * ND * sizeof(u16);
  u16*   e      = (u16*)ws;   ws += (size_t)E * ED * sizeof(u16);
  u16*   zs0    = (u16*)ws;   ws += (size_t)N * ED * sizeof(u16);
  u16*   zd0    = (u16*)ws;   ws += (size_t)N * ED * sizeof(u16);
  u16*   zs1    = (u16*)ws;   ws += (size_t)N * ED * sizeof(u16);
  u16*   zd1    = (u16*)ws;   ws += (size_t)N * ED * sizeof(u16);
  int*   noffs  = (int*)ws;   ws += ((size_t)N + 4) * sizeof(int);
  // contiguous zero-block: bcnt | cursor | mxu | sum  (single memset)
  int*   bcnt   = (int*)ws;   ws += (size_t)NBC_MAX * sizeof(int);
  int*   cursor = (int*)ws;   ws += (size_t)NBC_MAX * sizeof(int);
  unsigned int* mxu = (unsigned int*)ws; ws += (size_t)NG * sizeof(unsigned int);
  float* sum    = (float*)ws; ws += (size_t)NG * sizeof(float);
  int*   bbase  = (int*)ws;   ws += ((size_t)NBC_MAX + 4) * sizeof(int);
  float* logits = (float*)ws; ws += (size_t)NC * sizeof(float);
  int*   seg    = (int*)ws;   ws += (size_t)NC * sizeof(int);

  const int* srcp = edge_index;
  const int* dstp = edge_index + E;
  const int blk = 256;
  const size_t WE_STRIDE = (size_t)(2 * ND + ED) * ED;  // 72*8

  // one memset for all zeroed scratch: bcnt+cursor+mxu+sum
  hipMemsetAsync(bcnt, 0, (2 * (size_t)NBC_MAX + 2 * (size_t)NG) * sizeof(int),
                 stream);

  // binned two-phase counting sort (8-B packed records) + CSR offsets + init
  k_chist<<<(E + CHUNK_H - 1) / CHUNK_H, 1024, 0, stream>>>(dstp, bcnt, E, nbc);
  k_cscan<<<1, NBC_MAX, 0, stream>>>(bcnt, bbase, nbc);
  k_binA<<<(E + CHUNK - 1) / CHUNK, 1024, 0, stream>>>(srcp, dstp, ea, bbase,
                                                       cursor, binned, E, nbc);
  k_binB_init<<<nbc, 256, 0, stream>>>(binned, bbase, ssrc, ea_s, noffs,
                                       x, Wn_in, bn_in, We_l, be_l,
                                       h, zs0, zd0, N);

  // 8 lanes per node: 256-thread block covers 32 nodes
  const int ngrid8 = (N + 31) / 32;
  u16* zsc = zs0; u16* zdc = zd0;
  u16* zsn = zs1; u16* zdn = zd1;
  for (int l = 0; l < NL - 1; ++l) {
    const float* W3 = We_l + l * WE_STRIDE + (size_t)2 * ND * ED;
    const float* Wn = Wn_l + (size_t)l * (ND + ED) * ND;
    const float* bn = bn_l + (size_t)l * ND;
    const float* Wen = We_l + (l + 1) * WE_STRIDE;
    const float* ben = be_l + (size_t)(l + 1) * ED;
    if (l == 0) {
      k_layer<1><<<ngrid8, 256, 0, stream>>>(
          h, e, ea_s, ssrc, noffs, zsc, zdc, We_in, be_in, W3, Wn, bn,
          Wen, ben, zsn, zdn, N);
    } else {
      k_layer<0><<<ngrid8, 256, 0, stream>>>(
          h, e, ea_s, ssrc, noffs, zsc, zdc, We_in, be_in, W3, Wn, bn,
          Wen, ben, zsn, zdn, N);
    }
    u16* t;
    t = zsc; zsc = zsn; zsn = t;
    t = zdc; zdc = zdn; zdn = t;
  }

  {
    const int l = NL - 1;
    const float* W3 = We_l + l * WE_STRIDE + (size_t)2 * ND * ED;
    const float* Wn = Wn_l + (size_t)l * (ND + ED) * ND;
    const float* bn = bn_l + (size_t)l * ND;
    // 16 lanes per candidate
    k_cand<<<((size_t)NC * 16 + 255) / 256, 256, 0, stream>>>(
        h, e, zsc, zdc, ssrc, noffs, cand, batch, W3, Wn, bn, Wout, bout,
        logits, seg, mxu, NC);
  }
  k_expsum<<<(NC + blk - 1) / blk, blk, 0, stream>>>(logits, seg, mxu, sum, NC);
  k_final<<<(NC + blk - 1) / blk, blk, 0, stream>>>(logits, seg, sum,
                                                    (float*)d_out, NC);
}